// Round 5
// baseline (1034.272 us; speedup 1.0000x reference)
//
#include <hip/hip_runtime.h>

// Counting-sort + LDS accumulation (no global atomics anywhere).
// R4 -> R5 (k_accum was 559us, throughput-bound, not VALU/HBM/occupancy):
//   - SoA LDS accumulator acc[c][atom]: old [atom][c] layout strided x4 words
//     -> only 8/32 banks usable -> ~8-way conflicts on every ds_add. SoA makes
//     bank = dest%32 (random, ~2-way = free per m136).
//   - Nontemporal tuple loads + NT partials stores: keep the 3.2 MB charges
//     table resident in per-XCD L2 instead of letting the 205 MB tuple stream
//     evict it (gathers were falling to LLC).
//   - Explicit software pipeline in k_accum (prefetch next 4 tuples before
//     the ds_add phase) to break the VGPR=16 serial chain.
//   - k_hist: per-wave histogram replicas (4x less same-address ds serialization).

#define BLOCK   256
#define NBLK    1024       // edge chunks for hist/scatter (== rowscan width)
#define NBLK_LG 10
#define AB_LOG  10
#define A_B     1024       // atoms per bucket (16 KB LDS accumulator)
#define MAXNB   256

static __device__ __forceinline__ unsigned long long nt_u64(const void* p) {
    return __builtin_nontemporal_load((const unsigned long long*)p);
}
static __device__ __forceinline__ float nt_f32(const float* p) {
    return __builtin_nontemporal_load(p);
}
static __device__ __forceinline__ void nt_store(float* p, float v) {
    __builtin_nontemporal_store(v, p);
}

// ---- K1: per-block histogram, per-wave replicas -------------------------
__global__ __launch_bounds__(BLOCK) void k_hist(
    const int2* __restrict__ nbr, int* __restrict__ blk_hist,
    int n_edges, int nb)
{
    __shared__ int h[4 * MAXNB];
    for (int i = threadIdx.x; i < 4 * MAXNB; i += blockDim.x) h[i] = 0;
    __syncthreads();
    int* hw = h + (threadIdx.x >> 6) * MAXNB;
    int per = (n_edges + gridDim.x - 1) / gridDim.x;
    int lo = blockIdx.x * per;
    int hi = min(lo + per, n_edges);
    #pragma unroll 4
    for (int e = lo + threadIdx.x; e < hi; e += blockDim.x) {
        unsigned long long v = nt_u64(&nbr[e]);
        int ix = (int)(v & 0xffffffffu);
        int iy = (int)(v >> 32);
        atomicAdd(&hw[ix >> AB_LOG], 1);
        atomicAdd(&hw[iy >> AB_LOG], 1);
    }
    __syncthreads();
    for (int i = threadIdx.x; i < nb; i += blockDim.x)
        blk_hist[i * NBLK + blockIdx.x] =
            h[i] + h[MAXNB + i] + h[2 * MAXNB + i] + h[3 * MAXNB + i];
}

// ---- K2: exclusive scan of each bucket's row (NBLK entries) -------------
__global__ __launch_bounds__(NBLK) void k_rowscan(
    const int* __restrict__ blk_hist, int* __restrict__ offs,
    int* __restrict__ totals)
{
    __shared__ int a[NBLK];
    int b = blockIdx.x, t = threadIdx.x;
    int v = blk_hist[b * NBLK + t];
    a[t] = v;
    __syncthreads();
    for (int off = 1; off < NBLK; off <<= 1) {
        int x = (t >= off) ? a[t - off] : 0;
        __syncthreads();
        a[t] += x;
        __syncthreads();
    }
    offs[b * NBLK + t] = a[t] - v;       // exclusive within bucket
    if (t == NBLK - 1) totals[b] = a[t];
}

// ---- K3: bucket bases (parallel LDS scan, one block) --------------------
__global__ __launch_bounds__(MAXNB) void k_bases(
    const int* __restrict__ totals, int* __restrict__ bases, int nb)
{
    __shared__ int a[MAXNB];
    int t = threadIdx.x;
    int v = (t < nb) ? totals[t] : 0;
    a[t] = v;
    __syncthreads();
    for (int off = 1; off < MAXNB; off <<= 1) {
        int x = (t >= off) ? a[t - off] : 0;
        __syncthreads();
        a[t] += x;
        __syncthreads();
    }
    if (t < nb) bases[t] = a[t] - v;
}

// ---- K4: offs[i] += bases[i / NBLK] -------------------------------------
__global__ void k_addbase(int* __restrict__ offs, const int* __restrict__ bases, int n)
{
    int i = blockIdx.x * blockDim.x + threadIdx.x;
    if (i < n) offs[i] += bases[i >> NBLK_LG];
}

// ---- K5: counting-sort scatter of tuples --------------------------------
__global__ __launch_bounds__(BLOCK) void k_scatter(
    const int2* __restrict__ nbr, const float* __restrict__ dist,
    const int* __restrict__ offs, uint2* __restrict__ tuples,
    int n_edges, int nb)
{
    __shared__ int cur[MAXNB];
    for (int i = threadIdx.x; i < nb; i += blockDim.x)
        cur[i] = offs[i * NBLK + blockIdx.x];
    __syncthreads();
    int per = (n_edges + gridDim.x - 1) / gridDim.x;
    int lo = blockIdx.x * per;
    int hi = min(lo + per, n_edges);
    #pragma unroll 4
    for (int e = lo + threadIdx.x; e < hi; e += blockDim.x) {
        unsigned long long v = nt_u64(&nbr[e]);
        int ix = (int)(v & 0xffffffffu);
        int iy = (int)(v >> 32);
        float w = 0.5f / nt_f32(&dist[e]);
        unsigned wb = __float_as_uint(w);
        int pi = atomicAdd(&cur[ix >> AB_LOG], 1);
        tuples[pi] = make_uint2((unsigned)(ix & (A_B - 1)) | ((unsigned)iy << AB_LOG), wb);
        int pj = atomicAdd(&cur[iy >> AB_LOG], 1);
        tuples[pj] = make_uint2((unsigned)(iy & (A_B - 1)) | ((unsigned)ix << AB_LOG), wb);
    }
}

// ---- K6: per-(bucket,slice) LDS accumulation, SoA + pipelined -----------
__global__ __launch_bounds__(BLOCK) void k_accum(
    const uint2* __restrict__ tuples, const float4* __restrict__ charges,
    const int* __restrict__ bases, const int* __restrict__ totals,
    float* __restrict__ partials, int nslice)
{
    __shared__ float acc[4 * A_B];     // 16 KB, SoA: [channel][atom]
    int b = blockIdx.x / nslice;
    int s = blockIdx.x % nslice;
    for (int i = threadIdx.x; i < 4 * A_B; i += blockDim.x) acc[i] = 0.f;
    __syncthreads();
    int start = bases[b], cnt = totals[b];
    int lo = start + (int)((long long)cnt * s / nslice);
    int hi = start + (int)((long long)cnt * (s + 1) / nslice);

    const unsigned long long* tp = (const unsigned long long*)tuples;

    int p = lo + threadIdx.x;
    unsigned long long t0 = 0, t1 = 0, t2 = 0, t3 = 0;
    bool have = (p + 3 * BLOCK < hi);
    if (have) {
        t0 = nt_u64(&tp[p]);
        t1 = nt_u64(&tp[p + BLOCK]);
        t2 = nt_u64(&tp[p + 2 * BLOCK]);
        t3 = nt_u64(&tp[p + 3 * BLOCK]);
    }
    while (have) {
        int np = p + 4 * BLOCK;
        bool nhave = (np + 3 * BLOCK < hi);
        unsigned u0 = (unsigned)t0, u1 = (unsigned)t1;
        unsigned u2 = (unsigned)t2, u3 = (unsigned)t3;
        float4 c0 = charges[u0 >> AB_LOG];
        float4 c1 = charges[u1 >> AB_LOG];
        float4 c2 = charges[u2 >> AB_LOG];
        float4 c3 = charges[u3 >> AB_LOG];
        float w0 = __uint_as_float((unsigned)(t0 >> 32));
        float w1 = __uint_as_float((unsigned)(t1 >> 32));
        float w2 = __uint_as_float((unsigned)(t2 >> 32));
        float w3 = __uint_as_float((unsigned)(t3 >> 32));
        int d0 = u0 & (A_B - 1), d1 = u1 & (A_B - 1);
        int d2 = u2 & (A_B - 1), d3 = u3 & (A_B - 1);
        if (nhave) {                    // prefetch next batch before ds phase
            t0 = nt_u64(&tp[np]);
            t1 = nt_u64(&tp[np + BLOCK]);
            t2 = nt_u64(&tp[np + 2 * BLOCK]);
            t3 = nt_u64(&tp[np + 3 * BLOCK]);
        }
        atomicAdd(&acc[d0], c0.x * w0);
        atomicAdd(&acc[A_B + d0], c0.y * w0);
        atomicAdd(&acc[2 * A_B + d0], c0.z * w0);
        atomicAdd(&acc[3 * A_B + d0], c0.w * w0);
        atomicAdd(&acc[d1], c1.x * w1);
        atomicAdd(&acc[A_B + d1], c1.y * w1);
        atomicAdd(&acc[2 * A_B + d1], c1.z * w1);
        atomicAdd(&acc[3 * A_B + d1], c1.w * w1);
        atomicAdd(&acc[d2], c2.x * w2);
        atomicAdd(&acc[A_B + d2], c2.y * w2);
        atomicAdd(&acc[2 * A_B + d2], c2.z * w2);
        atomicAdd(&acc[3 * A_B + d2], c2.w * w2);
        atomicAdd(&acc[d3], c3.x * w3);
        atomicAdd(&acc[A_B + d3], c3.y * w3);
        atomicAdd(&acc[2 * A_B + d3], c3.z * w3);
        atomicAdd(&acc[3 * A_B + d3], c3.w * w3);
        p = np;
        have = nhave;
    }
    for (; p < hi; p += BLOCK) {
        unsigned long long t = nt_u64(&tp[p]);
        unsigned u = (unsigned)t;
        float4 c = charges[u >> AB_LOG];
        float w = __uint_as_float((unsigned)(t >> 32));
        int d = u & (A_B - 1);
        atomicAdd(&acc[d], c.x * w);
        atomicAdd(&acc[A_B + d], c.y * w);
        atomicAdd(&acc[2 * A_B + d], c.z * w);
        atomicAdd(&acc[3 * A_B + d], c.w * w);
    }
    __syncthreads();
    float* outp = partials + (size_t)blockIdx.x * (4 * A_B);
    for (int i = threadIdx.x; i < 4 * A_B; i += blockDim.x)
        nt_store(&outp[i], acc[i]);
}

// ---- K7: reduce nslice SoA partial images -> out (AoS float4) -----------
__global__ void k_final(const float* __restrict__ partials,
                        float4* __restrict__ out, int n_atoms, int nslice)
{
    int a = blockIdx.x * blockDim.x + threadIdx.x;
    if (a >= n_atoms) return;
    int b = a >> AB_LOG;
    int local = a & (A_B - 1);
    const float* base = partials + (size_t)(b * nslice) * (4 * A_B) + local;
    float r0 = 0.f, r1 = 0.f, r2 = 0.f, r3 = 0.f;
    for (int s = 0; s < nslice; ++s) {
        const float* p = base + (size_t)s * (4 * A_B);
        r0 += p[0];
        r1 += p[A_B];
        r2 += p[2 * A_B];
        r3 += p[3 * A_B];
    }
    out[a] = make_float4(r0, r1, r2, r3);
}

// ---- fallback (ws too small): agent-scope atomics, correct but 5 ms -----
__global__ __launch_bounds__(BLOCK) void edge_scatter_agent(
    const float4* __restrict__ charges, const int2* __restrict__ nbr,
    const float* __restrict__ dist, float* __restrict__ out, int n_edges)
{
    int e = blockIdx.x * blockDim.x + threadIdx.x;
    if (e >= n_edges) return;
    int2 ij = nbr[e];
    float w = 0.5f / dist[e];
    float4 cj = charges[ij.y];
    float4 ci = charges[ij.x];
    float* oi = out + (size_t)ij.x * 4;
    float* oj = out + (size_t)ij.y * 4;
    atomicAdd(oi + 0, cj.x * w); atomicAdd(oi + 1, cj.y * w);
    atomicAdd(oi + 2, cj.z * w); atomicAdd(oi + 3, cj.w * w);
    atomicAdd(oj + 0, ci.x * w); atomicAdd(oj + 1, ci.y * w);
    atomicAdd(oj + 2, ci.z * w); atomicAdd(oj + 3, ci.w * w);
}

extern "C" void kernel_launch(void* const* d_in, const int* in_sizes, int n_in,
                              void* d_out, int out_size, void* d_ws, size_t ws_size,
                              hipStream_t stream)
{
    // inputs: charges, cell, positions, neighbor_indices, neighbor_distances
    const float4* charges = (const float4*)d_in[0];
    const int2*   nbr     = (const int2*)d_in[3];
    const float*  dist    = (const float*)d_in[4];

    int n_edges = in_sizes[4];
    int n_atoms = out_size / 4;
    int nb = (n_atoms + A_B - 1) >> AB_LOG;     // 196 for 200000 atoms

    size_t n_pairs = (size_t)2 * n_edges;
    char*  w   = (char*)d_ws;
    size_t off = 0;
    auto alloc = [&](size_t bytes) -> void* {
        void* p = w + off;
        off += (bytes + 255) & ~(size_t)255;
        return p;
    };
    uint2* tuples   = (uint2*)alloc(n_pairs * sizeof(uint2));
    int*   blk_hist = (int*)  alloc((size_t)nb * NBLK * sizeof(int));
    int*   offs     = (int*)  alloc((size_t)nb * NBLK * sizeof(int));
    int*   totals   = (int*)  alloc((size_t)nb * sizeof(int));
    int*   bases    = (int*)  alloc((size_t)nb * sizeof(int));

    // adaptive slice count: partials = nb*nslice*A_B*4*4 bytes
    size_t slice_bytes = (size_t)nb * A_B * 4 * sizeof(float);
    int nslice = 16;
    while (nslice > 1 && off + (size_t)nslice * slice_bytes > ws_size) nslice >>= 1;
    float* partials = (float*)alloc((size_t)nslice * slice_bytes);

    if (off <= ws_size && nb <= MAXNB) {
        k_hist   <<<NBLK, BLOCK, 0, stream>>>(nbr, blk_hist, n_edges, nb);
        k_rowscan<<<nb,   NBLK,  0, stream>>>(blk_hist, offs, totals);
        k_bases  <<<1,    MAXNB, 0, stream>>>(totals, bases, nb);
        k_addbase<<<(nb * NBLK + 255) / 256, 256, 0, stream>>>(offs, bases, nb * NBLK);
        k_scatter<<<NBLK, BLOCK, 0, stream>>>(nbr, dist, offs, tuples, n_edges, nb);
        k_accum  <<<nb * nslice, BLOCK, 0, stream>>>(tuples, charges, bases, totals,
                                                     partials, nslice);
        k_final  <<<(n_atoms + 255) / 256, 256, 0, stream>>>(
            partials, (float4*)d_out, n_atoms, nslice);
    } else {
        hipMemsetAsync(d_out, 0, (size_t)out_size * sizeof(float), stream);
        edge_scatter_agent<<<(n_edges + BLOCK - 1) / BLOCK, BLOCK, 0, stream>>>(
            charges, nbr, dist, (float*)d_out, n_edges);
    }
}